// Round 4
// baseline (506.010 us; speedup 1.0000x reference)
//
#include <hip/hip_runtime.h>
#include <hip/hip_bf16.h>

typedef __attribute__((ext_vector_type(8))) short bf16x8;
typedef __attribute__((ext_vector_type(4))) float f32x4;

#define NE 8192
#define MT 32
#define DD 256
#define NAPP 262144
#define NSLOT (NE*MT)

static __device__ __forceinline__ unsigned short f2b(float x){
  union{float f; unsigned u;} v; v.f = x;
  unsigned r = (v.u + 0x7fffu + ((v.u>>16)&1u))>>16;
  return (unsigned short)r;
}
static __device__ __forceinline__ unsigned pk2(float a, float b){
  return (unsigned)f2b(a) | ((unsigned)f2b(b)<<16);
}

// ---- K0: Wg1,Wc1,Wg2,Wc2 f32 [512][256] -> bf16 transposed [256][512] each, packed in ws
__global__ void k_wt(const float* __restrict__ w0, const float* __restrict__ w1,
                     const float* __restrict__ w2, const float* __restrict__ w3,
                     unsigned short* __restrict__ wt){
  int idx = blockIdx.x*256 + threadIdx.x;
  int g = idx*4;
  int m = g >> 17;
  int r = g & 131071;
  int n = r >> 9;
  int k = r & 511;
  const float* W = (m==0)?w0:(m==1)?w1:(m==2)?w2:w3;
  unsigned short o0 = f2b(W[(k+0)*DD+n]);
  unsigned short o1 = f2b(W[(k+1)*DD+n]);
  unsigned short o2 = f2b(W[(k+2)*DD+n]);
  unsigned short o3 = f2b(W[(k+3)*DD+n]);
  uint2 u; u.x = (unsigned)o0 | ((unsigned)o1<<16); u.y = (unsigned)o2 | ((unsigned)o3<<16);
  *(uint2*)(wt + (size_t)m*131072 + n*512 + k) = u;
}

// ---- K1: last-write-wins winner per slot
__global__ void k_winner(const int* __restrict__ ei, const int* __restrict__ ti,
                         int* __restrict__ winner){
  int i = blockIdx.x*256 + threadIdx.x;
  atomicMax(&winner[ei[i]*MT + ti[i]], i);
}

// ---- K2: gate1, 64 token-slots (2 expressions) per block, fused dual-GEMM + token-mean.
// 256 threads = 4 waves; wave wc covers ALL 64 rows x 64 cols (wc*64..+63).
// A [64 rows][64 chunks of 16B] bf16 in LDS, chunk-addr ^ ((row&15)<<4); conflict-free
// staging (quarter-wave spans 16 rows). B double-buffered from global (L2-resident).
// No barrier inside the K-loop.
__global__ __launch_bounds__(256, 2)
void k_gate1(const float* __restrict__ expr, const float* __restrict__ sym,
             const float* __restrict__ bg, const float* __restrict__ bc,
             const unsigned short* __restrict__ Wgt, const unsigned short* __restrict__ Wct,
             const int* __restrict__ winner, const int* __restrict__ appsym,
             float* __restrict__ outcomb){
  __shared__ char A[64*1024];
  __shared__ int symidx[64];

  int tid  = threadIdx.x;
  int lane = tid & 63;
  int wc   = tid >> 6;            // 0..3 : 64-col slice
  int l15 = lane & 15, lg = lane >> 4;
  int s0 = blockIdx.x * 64;

  if (tid < 64){
    int wn = winner[s0 + tid];
    symidx[tid] = (wn >= 0) ? appsym[wn] : -1;
  }
  __syncthreads();

  { // stage A = [orig | sym] as bf16; row = tid&63, cpart = tid>>6, chunks cpart+4i
    int r = tid & 63;
    int cpart = tid >> 6;
    unsigned swz = (unsigned)((r & 15) << 4);
    char* arow = A + r*1024;
    const float* src = expr + (size_t)(s0+r)*DD;
    int si = symidx[r];
    #pragma unroll
    for (int i=0;i<8;i++){
      int chunk = cpart + i*4;          // 0..31 (orig half)
      int col = chunk*8;
      float4 x = *(const float4*)(src + col);
      float4 y = *(const float4*)(src + col + 4);
      uint4 u; u.x=pk2(x.x,x.y); u.y=pk2(x.z,x.w); u.z=pk2(y.x,y.y); u.w=pk2(y.z,y.w);
      *(uint4*)(arow + ((chunk*16) ^ swz)) = u;
    }
    if (si >= 0){
      const float* s2 = sym + (size_t)si*DD;
      #pragma unroll
      for (int i=0;i<8;i++){
        int chunk = 32 + cpart + i*4;   // 32..63 (sym half)
        int col = (chunk-32)*8;
        float4 x = *(const float4*)(s2 + col);
        float4 y = *(const float4*)(s2 + col + 4);
        uint4 u; u.x=pk2(x.x,x.y); u.y=pk2(x.z,x.w); u.z=pk2(y.x,y.y); u.w=pk2(y.z,y.w);
        *(uint4*)(arow + ((chunk*16) ^ swz)) = u;
      }
    } else {
      uint4 u = {0,0,0,0};
      #pragma unroll
      for (int i=0;i<8;i++){
        int chunk = 32 + cpart + i*4;
        *(uint4*)(arow + ((chunk*16) ^ swz)) = u;
      }
    }
  }
  __syncthreads();

  unsigned sw = (unsigned)(l15 << 4);
  const char* pa = A + l15*1024;
  const unsigned short* wgp = Wgt + (size_t)(wc*64 + l15)*512 + lg*8;
  const unsigned short* wcp = Wct + (size_t)(wc*64 + l15)*512 + lg*8;

  f32x4 accg[4][4], accc[4][4];
  f32x4 zz = {0.f,0.f,0.f,0.f};
  #pragma unroll
  for (int rt=0;rt<4;rt++)
    #pragma unroll
    for (int ct=0;ct<4;ct++){ accg[rt][ct]=zz; accc[rt][ct]=zz; }

  bf16x8 bgB[2][4], bcB[2][4];
  #pragma unroll
  for (int ct=0;ct<4;ct++){
    bgB[0][ct] = *(const bf16x8*)(wgp + ct*8192);
    bcB[0][ct] = *(const bf16x8*)(wcp + ct*8192);
  }

  #pragma unroll
  for (int ks=0; ks<16; ++ks){
    int cb = ks & 1, nb = cb ^ 1;
    if (ks < 15){
      #pragma unroll
      for (int ct=0;ct<4;ct++){
        bgB[nb][ct] = *(const bf16x8*)(wgp + (ks+1)*32 + ct*8192);
        bcB[nb][ct] = *(const bf16x8*)(wcp + (ks+1)*32 + ct*8192);
      }
    }
    int koff = (ks*64 + lg*16) ^ (int)sw;
    bf16x8 a[4];
    #pragma unroll
    for (int rt=0;rt<4;rt++)
      a[rt] = *(const bf16x8*)(pa + rt*16384 + koff);
    #pragma unroll
    for (int rt=0;rt<4;rt++){
      #pragma unroll
      for (int ct=0;ct<4;ct++){
        accg[rt][ct] = __builtin_amdgcn_mfma_f32_16x16x32_bf16(a[rt], bgB[cb][ct], accg[rt][ct], 0,0,0);
        accc[rt][ct] = __builtin_amdgcn_mfma_f32_16x16x32_bf16(a[rt], bcB[cb][ct], accc[rt][ct], 0,0,0);
      }
    }
  }

  float bgv[4], bcv[4];
  #pragma unroll
  for (int ct=0;ct<4;ct++){ int c = wc*64+ct*16+l15; bgv[ct]=bg[c]; bcv[ct]=bc[c]; }

  // epilogue: sigmoid gate, combine with exact f32 prev (global re-read, L2/L3-warm),
  // token-mean over each expression's 32 rows
  #pragma unroll
  for (int ct=0; ct<4; ++ct){
    int col = wc*64 + ct*16 + l15;
    #pragma unroll
    for (int e=0; e<2; ++e){
      float ssum = 0.f;
      #pragma unroll
      for (int rl=0; rl<2; ++rl){
        int rt = e*2 + rl;
        #pragma unroll
        for (int j=0;j<4;j++){
          int row = rt*16 + lg*4 + j;
          float prevv = expr[(size_t)(s0+row)*DD + col];
          float fr = 1.f/(1.f + __expf(-(accg[rt][ct][j] + bgv[ct])));
          float cand = fmaxf(accc[rt][ct][j] + bcv[ct], 0.f);
          float o = (symidx[row] >= 0) ? (fr*prevv + (1.f-fr)*cand) : prevv;
          ssum += o;
        }
      }
      ssum += __shfl_xor(ssum, 16);
      ssum += __shfl_xor(ssum, 32);
      if (lane < 16)
        outcomb[(size_t)(blockIdx.x*2 + e)*DD + col] = ssum * (1.f/32.f);
    }
  }
}

// ---- K3: gate2 over 64 expressions per block, in-place on d_out (unchanged, validated)
__global__ __launch_bounds__(1024)
void k_gate2(const float* __restrict__ prevn, const float* comb,
             const float* __restrict__ bg, const float* __restrict__ bc,
             const unsigned short* __restrict__ Wgt, const unsigned short* __restrict__ Wct,
             float* out){
  __shared__ char A[64*1024];

  int tid  = threadIdx.x;
  int lane = tid & 63;
  int wv   = tid >> 6;
  int wr = wv >> 3, wc = wv & 7;
  int l15 = lane & 15, lg = lane >> 4;
  int e0 = blockIdx.x * 64;

  { // stage A = [prev | combined]
    int row = tid >> 4, cb = (tid & 15)*16;
    unsigned swz = (unsigned)((row&7)<<4);
    const float* src = prevn + (size_t)(e0+row)*DD + cb;
    const float* s2  = comb  + (size_t)(e0+row)*DD + cb;
    char* arow = A + row*1024;
    #pragma unroll
    for (int i=0;i<2;i++){
      float4 x = *(const float4*)(src + i*8);
      float4 y = *(const float4*)(src + i*8 + 4);
      uint4 u; u.x=pk2(x.x,x.y); u.y=pk2(x.z,x.w); u.z=pk2(y.x,y.y); u.w=pk2(y.z,y.w);
      *(uint4*)(arow + (((cb+i*8)*2) ^ swz)) = u;
    }
    #pragma unroll
    for (int i=0;i<2;i++){
      float4 x = *(const float4*)(s2 + i*8);
      float4 y = *(const float4*)(s2 + i*8 + 4);
      uint4 u; u.x=pk2(x.x,x.y); u.y=pk2(x.z,x.w); u.z=pk2(y.x,y.y); u.w=pk2(y.z,y.w);
      *(uint4*)(arow + (((256+cb+i*8)*2) ^ swz)) = u;
    }
  }
  __syncthreads();

  unsigned swzL = (unsigned)((l15&7)<<4);
  const char* pa0 = A + (wr*32 + l15)*1024;
  const char* pa1 = pa0 + 16*1024;
  const unsigned short* wg0 = Wgt + (size_t)(wc*32 + l15)*512 + lg*8;
  const unsigned short* wc0 = Wct + (size_t)(wc*32 + l15)*512 + lg*8;

  f32x4 accg[2][2], accc[2][2];
  f32x4 zz = {0.f,0.f,0.f,0.f};
  #pragma unroll
  for (int ri=0;ri<2;ri++){ accg[ri][0]=zz; accg[ri][1]=zz; accc[ri][0]=zz; accc[ri][1]=zz; }

  for (int ks=0; ks<16; ++ks){
    int koff = (ks*64 + lg*16) ^ (int)swzL;
    bf16x8 a0 = *(const bf16x8*)(pa0 + koff);
    bf16x8 a1 = *(const bf16x8*)(pa1 + koff);
    int kw = ks*32;
    #pragma unroll
    for (int ct=0; ct<2; ++ct){
      bf16x8 b = *(const bf16x8*)(wg0 + ct*16*512 + kw);
      accg[0][ct] = __builtin_amdgcn_mfma_f32_16x16x32_bf16(a0, b, accg[0][ct], 0,0,0);
      accg[1][ct] = __builtin_amdgcn_mfma_f32_16x16x32_bf16(a1, b, accg[1][ct], 0,0,0);
    }
  }

  float bgv[2], bcv[2];
  #pragma unroll
  for (int ct=0;ct<2;ct++){ int c = wc*32+ct*16+l15; bgv[ct]=bg[c]; bcv[ct]=bc[c]; }
  #pragma unroll
  for (int ri=0;ri<2;ri++)
    #pragma unroll
    for (int ct=0;ct<2;ct++)
      #pragma unroll
      for (int j=0;j<4;j++)
        accg[ri][ct][j] = 1.f/(1.f + __expf(-(accg[ri][ct][j] + bgv[ct])));

  for (int ks=0; ks<16; ++ks){
    int koff = (ks*64 + lg*16) ^ (int)swzL;
    bf16x8 a0 = *(const bf16x8*)(pa0 + koff);
    bf16x8 a1 = *(const bf16x8*)(pa1 + koff);
    int kw = ks*32;
    #pragma unroll
    for (int ct=0; ct<2; ++ct){
      bf16x8 b = *(const bf16x8*)(wc0 + ct*16*512 + kw);
      accc[0][ct] = __builtin_amdgcn_mfma_f32_16x16x32_bf16(a0, b, accc[0][ct], 0,0,0);
      accc[1][ct] = __builtin_amdgcn_mfma_f32_16x16x32_bf16(a1, b, accc[1][ct], 0,0,0);
    }
  }

  #pragma unroll
  for (int ct=0; ct<2; ++ct){
    #pragma unroll
    for (int ri=0; ri<2; ++ri){
      #pragma unroll
      for (int j=0;j<4;j++){
        int row = wr*32 + ri*16 + lg*4 + j;
        int col = wc*32 + ct*16 + l15;
        int e = e0 + row;
        float prevv = prevn[(size_t)e*DD + col];
        float fr = accg[ri][ct][j];
        float cand = fmaxf(accc[ri][ct][j] + bcv[ct], 0.f);
        out[(size_t)e*DD + col] = fr*prevv + (1.f-fr)*cand;
      }
    }
  }
}

extern "C" void kernel_launch(void* const* d_in, const int* in_sizes, int n_in,
                              void* d_out, int out_size, void* d_ws, size_t ws_size,
                              hipStream_t stream){
  const float* expr = (const float*)d_in[0];
  const float* sym  = (const float*)d_in[1];
  const float* prevn= (const float*)d_in[2];
  const float* Wg1 = (const float*)d_in[3];
  const float* bg1 = (const float*)d_in[4];
  const float* Wc1 = (const float*)d_in[5];
  const float* bc1 = (const float*)d_in[6];
  const float* Wg2 = (const float*)d_in[7];
  const float* bg2 = (const float*)d_in[8];
  const float* Wc2 = (const float*)d_in[9];
  const float* bc2 = (const float*)d_in[10];
  const int* aei = (const int*)d_in[11];
  const int* ati = (const int*)d_in[12];
  const int* asi = (const int*)d_in[13];
  float* outp = (float*)d_out;

  int* winner = (int*)d_ws;
  unsigned short* wt = (unsigned short*)((char*)d_ws + (1<<20));

  hipMemsetAsync(winner, 0xFF, NSLOT*sizeof(int), stream);
  k_wt<<<512, 256, 0, stream>>>(Wg1, Wc1, Wg2, Wc2, wt);
  k_winner<<<NAPP/256, 256, 0, stream>>>(aei, ati, winner);

  k_gate1<<<NSLOT/64, 256, 0, stream>>>(expr, sym, bg1, bc1,
                                        wt, wt + 131072, winner, asi, outp);
  k_gate2<<<NE/64, 1024, 0, stream>>>(prevn, outp, bg2, bc2,
                                      wt + 262144, wt + 393216, outp);
}

// Round 5
// 278.278 us; speedup vs baseline: 1.8184x; 1.8184x over previous
//
#include <hip/hip_runtime.h>
#include <hip/hip_bf16.h>

typedef __attribute__((ext_vector_type(8))) short bf16x8;
typedef __attribute__((ext_vector_type(4))) float f32x4;

#define NE 8192
#define MT 32
#define DD 256
#define NAPP 262144
#define NSLOT (NE*MT)
#define NSYM 50000
#define NSYMP 50048

// ws layout (bytes)
#define WS_WINNER 0
#define WS_WTSW   (1u<<20)
#define WS_WTLIN  (2u<<20)
#define WS_SYMGC  (3u<<20)   // NSYMP*512*2 = 51.2MB -> total ~54.4MB

static __device__ __forceinline__ unsigned short f2b(float x){
  union{float f; unsigned u;} v; v.f = x;
  unsigned r = (v.u + 0x7fffu + ((v.u>>16)&1u))>>16;
  return (unsigned short)r;
}
static __device__ __forceinline__ unsigned pk2(float a, float b){
  return (unsigned)f2b(a) | ((unsigned)f2b(b)<<16);
}
static __device__ __forceinline__ float bfl(unsigned w){ union{unsigned u; float f;} v; v.u = w<<16; return v.f; }
static __device__ __forceinline__ float bfh(unsigned w){ union{unsigned u; float f;} v; v.u = w & 0xffff0000u; return v.f; }
static __device__ __forceinline__ float frombf(unsigned short u){ union{unsigned x; float f;} v; v.x = ((unsigned)u)<<16; return v.f; }

static __device__ __forceinline__ void gload16(const void* g, void* l){
  __builtin_amdgcn_global_load_lds((const __attribute__((address_space(1))) void*)g,
                                   (__attribute__((address_space(3))) void*)l, 16, 0, 0);
}

// ---- K0: weights f32 [512][256] -> bf16 transposed, TWO copies:
// wt_lin[m][n][k] (k-contig) for k_gate2, and wt_sw pre-swizzled for LDS staging:
// byte(m,n,k) = m*256K + n*1024 + (k>>5)*64 + (((k>>3) + (n>>1))&3)*16 + (k&7)*2
__global__ void k_wt(const float* __restrict__ w0, const float* __restrict__ w1,
                     const float* __restrict__ w2, const float* __restrict__ w3,
                     char* __restrict__ wtsw, unsigned short* __restrict__ wtlin){
  int g = blockIdx.x*256 + threadIdx.x;   // m(2) kg(6) n(8)
  int m = g >> 14;
  int kg = (g >> 8) & 63;
  int n = g & 255;
  const float* W = (m==0)?w0:(m==1)?w1:(m==2)?w2:w3;
  unsigned short v[8];
  #pragma unroll
  for (int i=0;i<8;i++) v[i] = f2b(W[(kg*8+i)*DD + n]);
  uint4 u;
  u.x = (unsigned)v[0] | ((unsigned)v[1]<<16);
  u.y = (unsigned)v[2] | ((unsigned)v[3]<<16);
  u.z = (unsigned)v[4] | ((unsigned)v[5]<<16);
  u.w = (unsigned)v[6] | ((unsigned)v[7]<<16);
  *(uint4*)(wtlin + (size_t)m*131072 + n*512 + kg*8) = u;
  int rot = ((kg & 3) + (n >> 1)) & 3;
  *(uint4*)(wtsw + (size_t)m*262144 + n*1024 + (kg>>2)*64 + rot*16) = u;
}

// ---- K1: last-write-wins winner per slot
__global__ void k_winner(const int* __restrict__ ei, const int* __restrict__ ti,
                         int* __restrict__ winner){
  int i = blockIdx.x*256 + threadIdx.x;
  atomicMax(&winner[ei[i]*MT + ti[i]], i);
}

// ---- K_syms: SymGC[s][0:256] = sym[s] @ Wg1[256:512,:], [256:512] = sym[s] @ Wc1[256:512,:]
// 64 rows/block, 8 waves (G-waves 0-3, C-waves 4-7), wave tile 64r x 64c, bf16 out.
__global__ __launch_bounds__(512, 4)
void k_syms(const float* __restrict__ sym, const char* __restrict__ wtsw,
            unsigned short* __restrict__ symgc){
  __shared__ char Abuf[32768];
  __shared__ char Bbuf[32768];

  int tid = threadIdx.x, lane = tid & 63, wv = tid >> 6;
  int l15 = lane & 15, lg = lane >> 4;
  int wq = wv & 3; bool isC = wv >= 4;
  int s0 = blockIdx.x * 64;

  { // stage A [64 rows][256 k] bf16, chunk-addr ^ ((row&15)<<4)
    int r = tid >> 3;
    int row = s0 + r;
    char* arow = Abuf + r*512;
    unsigned swz = (unsigned)((r & 15) << 4);
    if (row < NSYM){
      const float* src = sym + (size_t)row*DD;
      #pragma unroll
      for (int i=0;i<4;i++){
        int c = (tid & 7) + i*8;
        float4 x = *(const float4*)(src + c*8);
        float4 y = *(const float4*)(src + c*8 + 4);
        uint4 u; u.x=pk2(x.x,x.y); u.y=pk2(x.z,x.w); u.z=pk2(y.x,y.y); u.w=pk2(y.z,y.w);
        *(uint4*)(arow + ((c*16) ^ swz)) = u;
      }
    } else {
      uint4 u = {0,0,0,0};
      #pragma unroll
      for (int i=0;i<4;i++){
        int c = (tid & 7) + i*8;
        *(uint4*)(arow + ((c*16) ^ swz)) = u;
      }
    }
  }
  __syncthreads();

  f32x4 acc[4][4];
  f32x4 zz = {0.f,0.f,0.f,0.f};
  #pragma unroll
  for (int rt=0;rt<4;rt++)
    #pragma unroll
    for (int ct=0;ct<4;ct++) acc[rt][ct]=zz;

  const char* wbG = wtsw;              // Wg1
  const char* wbC = wtsw + 262144;     // Wc1

  for (int kt=0; kt<8; ++kt){
    __syncthreads();
    #pragma unroll
    for (int i=0;i<4;i++){
      int n = wv*64 + i*16 + (lane>>2);
      const char* src = ((n < 256)? wbG : wbC) + (size_t)(n & 255)*1024 + (8+kt)*64 + (lane&3)*16;
      gload16(src, Bbuf + n*64 + (lane&3)*16);
    }
    __syncthreads();
    int koff = kt*64 + lg*16;
    bf16x8 a[4], b[4];
    #pragma unroll
    for (int rt=0;rt<4;rt++)
      a[rt] = *(const bf16x8*)(Abuf + (rt*16 + l15)*512 + (koff ^ (l15<<4)));
    #pragma unroll
    for (int ct=0;ct<4;ct++){
      int nn = (isC?256:0) + wq*64 + ct*16 + l15;
      b[ct] = *(const bf16x8*)(Bbuf + nn*64 + (((lg + (nn>>1)) & 3)<<4));
    }
    #pragma unroll
    for (int rt=0;rt<4;rt++)
      #pragma unroll
      for (int ct=0;ct<4;ct++)
        acc[rt][ct] = __builtin_amdgcn_mfma_f32_16x16x32_bf16(a[rt], b[ct], acc[rt][ct], 0,0,0);
  }

  int cb = (isC?256:0) + wq*64;
  #pragma unroll
  for (int rt=0;rt<4;rt++)
    #pragma unroll
    for (int ct=0;ct<4;ct++)
      #pragma unroll
      for (int j=0;j<4;j++){
        int row = s0 + rt*16 + lg*4 + j;
        symgc[(size_t)row*512 + cb + ct*16 + l15] = f2b(acc[rt][ct][j]);
      }
}

// ---- K2: gate1. 64 slots (2 expr)/block, 8 waves. K=256 (orig only; sym part via SymGC gather).
// G-waves compute gate logits, C-waves candidate logits; cross-wave combine via LDS reuse.
__global__ __launch_bounds__(512, 4)
void k_gate1(const float* __restrict__ expr, const char* __restrict__ wtsw,
             const float* __restrict__ bg, const float* __restrict__ bc,
             const int* __restrict__ winner, const int* __restrict__ appsym,
             const unsigned short* __restrict__ symgc,
             float* __restrict__ outcomb){
  __shared__ char Abuf[32768];
  __shared__ char Bbuf[32768];

  int tid = threadIdx.x, lane = tid & 63, wv = tid >> 6;
  int l15 = lane & 15, lg = lane >> 4;
  int wq = wv & 3; bool isC = wv >= 4;
  int s0 = blockIdx.x * 64;

  // per-lane symbol index for row = lane (used via __shfl)
  int wn = winner[s0 + lane];
  int sidv = (wn >= 0) ? appsym[wn] : -1;

  { // stage A = orig expr [64][256] bf16
    int r = tid >> 3;
    const float* src = expr + (size_t)(s0 + r)*DD;
    char* arow = Abuf + r*512;
    unsigned swz = (unsigned)((r & 15) << 4);
    #pragma unroll
    for (int i=0;i<4;i++){
      int c = (tid & 7) + i*8;
      float4 x = *(const float4*)(src + c*8);
      float4 y = *(const float4*)(src + c*8 + 4);
      uint4 u; u.x=pk2(x.x,x.y); u.y=pk2(x.z,x.w); u.z=pk2(y.x,y.y); u.w=pk2(y.z,y.w);
      *(uint4*)(arow + ((c*16) ^ swz)) = u;
    }
  }
  __syncthreads();

  f32x4 acc[4][4];
  f32x4 zz = {0.f,0.f,0.f,0.f};
  #pragma unroll
  for (int rt=0;rt<4;rt++)
    #pragma unroll
    for (int ct=0;ct<4;ct++) acc[rt][ct]=zz;

  const char* wbG = wtsw;
  const char* wbC = wtsw + 262144;

  for (int kt=0; kt<8; ++kt){
    __syncthreads();
    #pragma unroll
    for (int i=0;i<4;i++){
      int n = wv*64 + i*16 + (lane>>2);
      const char* src = ((n < 256)? wbG : wbC) + (size_t)(n & 255)*1024 + kt*64 + (lane&3)*16;
      gload16(src, Bbuf + n*64 + (lane&3)*16);
    }
    __syncthreads();
    int koff = kt*64 + lg*16;
    bf16x8 a[4], b[4];
    #pragma unroll
    for (int rt=0;rt<4;rt++)
      a[rt] = *(const bf16x8*)(Abuf + (rt*16 + l15)*512 + (koff ^ (l15<<4)));
    #pragma unroll
    for (int ct=0;ct<4;ct++){
      int nn = (isC?256:0) + wq*64 + ct*16 + l15;
      b[ct] = *(const bf16x8*)(Bbuf + nn*64 + (((lg + (nn>>1)) & 3)<<4));
    }
    #pragma unroll
    for (int rt=0;rt<4;rt++)
      #pragma unroll
      for (int ct=0;ct<4;ct++)
        acc[rt][ct] = __builtin_amdgcn_mfma_f32_16x16x32_bf16(a[rt], b[ct], acc[rt][ct], 0,0,0);
  }

  __syncthreads();   // K-loop done; reuse Abuf (f) / Bbuf (cand), col-major [256 cols][64 rows bf16]
  char* fbuf = Abuf;
  char* cbuf = Bbuf;
  char* obuf = isC ? cbuf : fbuf;

  const float* bias = isC ? bc : bg;
  float bv[4];
  #pragma unroll
  for (int ct=0;ct<4;ct++) bv[ct] = bias[wq*64 + ct*16 + l15];

  #pragma unroll
  for (int rt=0;rt<4;rt++){
    int rowb = rt*16 + lg*4;
    int sid[4];
    #pragma unroll
    for (int j=0;j<4;j++){ int s = __shfl(sidv, rowb + j); sid[j] = (s < 0) ? 0 : s; }
    float sv[4][4];
    #pragma unroll
    for (int j=0;j<4;j++)
      #pragma unroll
      for (int ct=0;ct<4;ct++)
        sv[j][ct] = frombf(symgc[(size_t)sid[j]*512 + (isC?256:0) + wq*64 + ct*16 + l15]);
    #pragma unroll
    for (int ct=0;ct<4;ct++){
      float o[4];
      #pragma unroll
      for (int j=0;j<4;j++){
        float x = acc[rt][ct][j] + sv[j][ct] + bv[ct];
        o[j] = isC ? fmaxf(x, 0.f) : 1.f/(1.f + __expf(-x));
      }
      int col = wq*64 + ct*16 + l15;
      uint2 pw; pw.x = pk2(o[0], o[1]); pw.y = pk2(o[2], o[3]);
      *(uint2*)(obuf + ((col*128 + rowb*2) ^ ((col&15)<<3))) = pw;
    }
  }
  __syncthreads();

  { // combine + token-mean: wave wv -> expr eL = wv>>2, col quarter q = wv&3; lane = col
    int eL = wv >> 2, q = wv & 3;
    int col = q*64 + lane;
    float ssum = 0.f;
    #pragma unroll
    for (int i=0;i<8;i++){
      unsigned xr = (unsigned)((col*128 + eL*64 + i*8) ^ ((col&15)<<3));
      uint2 fu = *(const uint2*)(fbuf + xr);
      uint2 cu = *(const uint2*)(cbuf + xr);
      float fvv[4] = { bfl(fu.x), bfh(fu.x), bfl(fu.y), bfh(fu.y) };
      float cvv[4] = { bfl(cu.x), bfh(cu.x), bfl(cu.y), bfh(cu.y) };
      #pragma unroll
      for (int j=0;j<4;j++){
        int row = eL*32 + i*4 + j;
        float pv = expr[(size_t)(s0 + row)*DD + col];
        int sact = __shfl(sidv, row);
        ssum += (sact >= 0) ? (fvv[j]*pv + (1.f - fvv[j])*cvv[j]) : pv;
      }
    }
    outcomb[(size_t)(blockIdx.x*2 + eL)*DD + col] = ssum * (1.f/32.f);
  }
}

// ---- K3: gate2 over 64 expressions per block, in-place on d_out (validated; uses wt_lin)
__global__ __launch_bounds__(1024)
void k_gate2(const float* __restrict__ prevn, const float* comb,
             const float* __restrict__ bg, const float* __restrict__ bc,
             const unsigned short* __restrict__ Wgt, const unsigned short* __restrict__ Wct,
             float* out){
  __shared__ char A[64*1024];

  int tid  = threadIdx.x;
  int lane = tid & 63;
  int wv   = tid >> 6;
  int wr = wv >> 3, wc = wv & 7;
  int l15 = lane & 15, lg = lane >> 4;
  int e0 = blockIdx.x * 64;

  { // stage A = [prev | combined]
    int row = tid >> 4, cb = (tid & 15)*16;
    unsigned swz = (unsigned)((row&7)<<4);
    const float* src = prevn + (size_t)(e0+row)*DD + cb;
    const float* s2  = comb  + (size_t)(e0+row)*DD + cb;
    char* arow = A + row*1024;
    #pragma unroll
    for (int i=0;i<2;i++){
      float4 x = *(const float4*)(src + i*8);
      float4 y = *(const float4*)(src + i*8 + 4);
      uint4 u; u.x=pk2(x.x,x.y); u.y=pk2(x.z,x.w); u.z=pk2(y.x,y.y); u.w=pk2(y.z,y.w);
      *(uint4*)(arow + (((cb+i*8)*2) ^ swz)) = u;
    }
    #pragma unroll
    for (int i=0;i<2;i++){
      float4 x = *(const float4*)(s2 + i*8);
      float4 y = *(const float4*)(s2 + i*8 + 4);
      uint4 u; u.x=pk2(x.x,x.y); u.y=pk2(x.z,x.w); u.z=pk2(y.x,y.y); u.w=pk2(y.z,y.w);
      *(uint4*)(arow + (((256+cb+i*8)*2) ^ swz)) = u;
    }
  }
  __syncthreads();

  unsigned swzL = (unsigned)((l15&7)<<4);
  const char* pa0 = A + (wr*32 + l15)*1024;
  const char* pa1 = pa0 + 16*1024;
  const unsigned short* wg0 = Wgt + (size_t)(wc*32 + l15)*512 + lg*8;
  const unsigned short* wc0 = Wct + (size_t)(wc*32 + l15)*512 + lg*8;

  f32x4 accg[2][2], accc[2][2];
  f32x4 zz = {0.f,0.f,0.f,0.f};
  #pragma unroll
  for (int ri=0;ri<2;ri++){ accg[ri][0]=zz; accg[ri][1]=zz; accc[ri][0]=zz; accc[ri][1]=zz; }

  for (int ks=0; ks<16; ++ks){
    int koff = (ks*64 + lg*16) ^ (int)swzL;
    bf16x8 a0 = *(const bf16x8*)(pa0 + koff);
    bf16x8 a1 = *(const bf16x8*)(pa1 + koff);
    int kw = ks*32;
    #pragma unroll
    for (int ct=0; ct<2; ++ct){
      bf16x8 b = *(const bf16x8*)(wg0 + ct*16*512 + kw);
      accg[0][ct] = __builtin_amdgcn_mfma_f32_16x16x32_bf16(a0, b, accg[0][ct], 0,0,0);
      accg[1][ct] = __builtin_amdgcn_mfma_f32_16x16x32_bf16(a1, b, accg[1][ct], 0,0,0);
    }
  }

  float bgv[2], bcv[2];
  #pragma unroll
  for (int ct=0;ct<2;ct++){ int c = wc*32+ct*16+l15; bgv[ct]=bg[c]; bcv[ct]=bc[c]; }
  #pragma unroll
  for (int ri=0;ri<2;ri++)
    #pragma unroll
    for (int ct=0;ct<2;ct++)
      #pragma unroll
      for (int j=0;j<4;j++)
        accg[ri][ct][j] = 1.f/(1.f + __expf(-(accg[ri][ct][j] + bgv[ct])));

  for (int ks=0; ks<16; ++ks){
    int koff = (ks*64 + lg*16) ^ (int)swzL;
    bf16x8 a0 = *(const bf16x8*)(pa0 + koff);
    bf16x8 a1 = *(const bf16x8*)(pa1 + koff);
    int kw = ks*32;
    #pragma unroll
    for (int ct=0; ct<2; ++ct){
      bf16x8 b = *(const bf16x8*)(wc0 + ct*16*512 + kw);
      accc[0][ct] = __builtin_amdgcn_mfma_f32_16x16x32_bf16(a0, b, accc[0][ct], 0,0,0);
      accc[1][ct] = __builtin_amdgcn_mfma_f32_16x16x32_bf16(a1, b, accc[1][ct], 0,0,0);
    }
  }

  #pragma unroll
  for (int ct=0; ct<2; ++ct){
    #pragma unroll
    for (int ri=0; ri<2; ++ri){
      #pragma unroll
      for (int j=0;j<4;j++){
        int row = wr*32 + ri*16 + lg*4 + j;
        int col = wc*32 + ct*16 + l15;
        int e = e0 + row;
        float prevv = prevn[(size_t)e*DD + col];
        float fr = accg[ri][ct][j];
        float cand = fmaxf(accc[ri][ct][j] + bcv[ct], 0.f);
        out[(size_t)e*DD + col] = fr*prevv + (1.f-fr)*cand;
      }
    }
  }
}

extern "C" void kernel_launch(void* const* d_in, const int* in_sizes, int n_in,
                              void* d_out, int out_size, void* d_ws, size_t ws_size,
                              hipStream_t stream){
  const float* expr = (const float*)d_in[0];
  const float* sym  = (const float*)d_in[1];
  const float* prevn= (const float*)d_in[2];
  const float* Wg1 = (const float*)d_in[3];
  const float* bg1 = (const float*)d_in[4];
  const float* Wc1 = (const float*)d_in[5];
  const float* bc1 = (const float*)d_in[6];
  const float* Wg2 = (const float*)d_in[7];
  const float* bg2 = (const float*)d_in[8];
  const float* Wc2 = (const float*)d_in[9];
  const float* bc2 = (const float*)d_in[10];
  const int* aei = (const int*)d_in[11];
  const int* ati = (const int*)d_in[12];
  const int* asi = (const int*)d_in[13];
  float* outp = (float*)d_out;

  char* wsb = (char*)d_ws;
  int* winner = (int*)(wsb + WS_WINNER);
  char* wtsw = wsb + WS_WTSW;
  unsigned short* wtlin = (unsigned short*)(wsb + WS_WTLIN);
  unsigned short* symgc = (unsigned short*)(wsb + WS_SYMGC);

  hipMemsetAsync(winner, 0xFF, NSLOT*sizeof(int), stream);
  k_wt<<<256, 256, 0, stream>>>(Wg1, Wc1, Wg2, Wc2, wtsw, wtlin);
  k_winner<<<NAPP/256, 256, 0, stream>>>(aei, ati, winner);
  k_syms<<<NSYMP/64, 512, 0, stream>>>(sym, wtsw, symgc);
  k_gate1<<<NSLOT/64, 512, 0, stream>>>(expr, wtsw, bg1, bc1, winner, asi, symgc, outp);
  k_gate2<<<NE/64, 1024, 0, stream>>>(prevn, outp, bg2, bc2,
                                      wtlin + 262144, wtlin + 393216, outp);
}